// Round 11
// baseline (250.091 us; speedup 1.0000x reference)
//
#include <hip/hip_runtime.h>
#include <math.h>

#define NN 50          // neighbours
#define DD 128         // embedding dim
#define MT 4           // 4 m-tiles of 16 rows (50 padded to 64)
#define KT 4           // 4 k-tiles of 32 (K=128)
#define NIT 64         // b's per block  (grid = B/NIT = 512 = 2 blocks/CU)
#define TILE_H 12800   // 50 rows * 256 B (fp16 tile)
#define NBUF 4

typedef __attribute__((ext_vector_type(4))) float  f32x4;
typedef __attribute__((ext_vector_type(2))) __fp16 f16x2;   // cvt_pkrtz return type
typedef __attribute__((ext_vector_type(4))) __fp16 f16x4;
typedef __attribute__((ext_vector_type(8))) __fp16 f16x8;

// fp32 scratch for W@A1 / W@A2, then fp16 transposed weight tables.
__device__ float g_WA1f[DD * DD];
__device__ float g_WA2f[DD * DD];
__device__ __attribute__((aligned(16))) __fp16 g_Wt[2 * DD * DD];  // [col 0..255][k]: [W | W@A2]^T
__device__ __attribute__((aligned(16))) __fp16 g_W1t[DD * DD];     // [col d][k]     : (W@A1)^T

__global__ void compute_WA(const float* __restrict__ W,
                           const float* __restrict__ A_w) {
    const int d = threadIdx.x, k = blockIdx.x, m = blockIdx.y;
    const float* __restrict__ A = A_w + (size_t)m * DD * DD;
    float acc = 0.f;
#pragma unroll 8
    for (int j = 0; j < DD; ++j)
        acc = fmaf(W[k * DD + j], A[j * DD + d], acc);
    if (m == 0) g_WA1f[k * DD + d] = acc;
    else        g_WA2f[k * DD + d] = acc;
}

__global__ void cvt_weights(const float* __restrict__ W) {
    const int n = blockIdx.x;      // 0..383
    const int k = threadIdx.x;     // 0..127
    if (n < DD)          g_Wt[n * DD + k]             = (__fp16)W[k * DD + n];
    else if (n < 2 * DD) g_Wt[n * DD + k]             = (__fp16)g_WA2f[k * DD + (n - DD)];
    else                 g_W1t[(n - 2 * DD) * DD + k] = (__fp16)g_WA1f[k * DD + (n - 2 * DD)];
}

// 8 consecutive fp32 -> 8 fp16 (packed RTZ converts, 4 instrs)
__device__ __forceinline__ f16x8 cvt8(float4 f0, float4 f1) {
    union { f16x2 h[4]; f16x8 v; } u;
    u.h[0] = __builtin_amdgcn_cvt_pkrtz(f0.x, f0.y);
    u.h[1] = __builtin_amdgcn_cvt_pkrtz(f0.z, f0.w);
    u.h[2] = __builtin_amdgcn_cvt_pkrtz(f1.x, f1.y);
    u.h[3] = __builtin_amdgcn_cvt_pkrtz(f1.z, f1.w);
    return u.v;
}

#define MFMA(a, b, c) __builtin_amdgcn_mfma_f32_16x16x32_f16((a), (b), (c), 0, 0, 0)

// v11: r10 structure (reg-staged, 512 thr / 8 waves, 16 cols/wave, <=128 VGPR)
// but TWO tiles per sync period: 4 LDS buffers, two staging reg sets, one
// lgkm-drain + one barrier per 2 tiles. r10's 4030 cy/tile vs ~2500 HBM
// budget was the serial chain [vmcnt->ds_write->ds_read->MFMA->softmax->
// drain->barrier] synced every tile; halving sync frequency + longer
// uninterrupted compute runs attacks exactly that. pxa_lds in fp16 to keep
// LDS at 67.6 KB (2 blocks/CU).
__global__ __launch_bounds__(512, 4)
void attn_mfma(const float* __restrict__ x,
               const float* __restrict__ nbr,
               const float* __restrict__ A_b,
               float* __restrict__ out, int B) {
    __shared__ __attribute__((aligned(16))) char tiles[NBUF][TILE_H]; // 51.2 KB
    __shared__ __fp16 pxa_lds[NIT][DD];                               // 16.4 KB

    const int tid  = threadIdx.x;
    const int w    = tid >> 6;     // 0..7
    const int lane = tid & 63;
    const int c    = lane & 15;    // A-row / B-col / D-col lane index
    const int g    = lane >> 4;    // k-group / D-row group
    const size_t b0 = (size_t)blockIdx.x * NIT;
    const int col  = 16 * w + c;   // this wave's output column

    // ---- Phase A: pxa_lds[i][col] = A_b[col] + (x[b0+i] @ WA1)[col] ----
    {
        f32x4 pacc[MT];
#pragma unroll
        for (int mt = 0; mt < MT; ++mt) pacc[mt] = (f32x4)0.f;
#pragma unroll
        for (int mt = 0; mt < MT; ++mt) {
            long brow = (long)b0 + 16 * mt + c;
            if (brow > B - 1) brow = B - 1;
            const float4* __restrict__ xp =
                reinterpret_cast<const float4*>(x + brow * DD);
#pragma unroll
            for (int kt = 0; kt < KT; ++kt) {
                const f16x8 a = cvt8(xp[8 * kt + 2 * g], xp[8 * kt + 2 * g + 1]);
                const f16x8 bw = *reinterpret_cast<const f16x8*>(
                    g_W1t + col * DD + 32 * kt + 8 * g);
                pacc[mt] = MFMA(a, bw, pacc[mt]);
            }
        }
        const float ab = A_b[col];
#pragma unroll
        for (int mt = 0; mt < MT; ++mt)
#pragma unroll
            for (int r = 0; r < 4; ++r)
                pxa_lds[16 * mt + 4 * g + r][col] = (__fp16)(pacc[mt][r] + ab);
    }

    // ---- B fragments (this wave's 16 cols, parts W and WA2), pinned ----
    f16x8 bF[2][KT];               // 32 VGPRs
#pragma unroll
    for (int p = 0; p < 2; ++p)
#pragma unroll
        for (int kt = 0; kt < KT; ++kt) {
            bF[p][kt] = *reinterpret_cast<const f16x8*>(
                g_Wt + (p * DD + col) * DD + 32 * kt + 8 * g);
            asm volatile("" : "+v"(bF[p][kt]));   // no remat/sink
        }

    // ---- two staging reg sets (tiles arrive two per period) ----
    float4 raA[4], raB[4];         // 32 VGPRs

    auto load_tile = [&](float4 (&ra)[4], int it) {
        int itc = it < NIT ? it : NIT - 1;        // tail: harmless re-load
        size_t bidx = b0 + (size_t)itc;
        if (bidx > (size_t)(B - 1)) bidx = (size_t)(B - 1);
        const float4* __restrict__ nb4 =
            reinterpret_cast<const float4*>(nbr + bidx * (size_t)(NN * DD));
#pragma unroll
        for (int j = 0; j < 4; ++j) {
            const int p = w + 8 * j;              // wave-uniform pass id
            if (p < 25) ra[j] = nb4[p * 64 + lane];
        }
    };

    // fp16 tile row = 256 B; byte addr XOR-swizzled by ((row&7)<<4).
    auto write_tile = [&](float4 (&ra)[4], char* dst) {
#pragma unroll
        for (int j = 0; j < 4; ++j) {
            const int p = w + 8 * j;
            if (p < 25) {
                const int lb  = p * 512 + lane * 8;   // fp16-tile byte offset
                const int row = lb >> 8;
                const int ad  = lb ^ ((row & 7) << 4);
                union { f16x2 h[2]; f16x4 v; } u;
                u.h[0] = __builtin_amdgcn_cvt_pkrtz(ra[j].x, ra[j].y);
                u.h[1] = __builtin_amdgcn_cvt_pkrtz(ra[j].z, ra[j].w);
                *reinterpret_cast<f16x4*>(dst + ad) = u.v;   // ds_write_b64
            }
        }
    };

    const float m0v = (g == 0) ? 1.f : 0.f;  // rows 48,49 valid iff g==0 (mt=3,r<2)

    auto compute_tile = [&](int i) {
        const char* __restrict__ tile = tiles[i & (NBUF - 1)];
        f32x4 acc[MT][2];
#pragma unroll
        for (int mt = 0; mt < MT; ++mt)
#pragma unroll
            for (int p = 0; p < 2; ++p) acc[mt][p] = (f32x4)0.f;

#pragma unroll
        for (int mt = 0; mt < MT; ++mt) {
            int row = 16 * mt + c;
            if (row > NN - 1) row = NN - 1;  // pad rows masked in softmax
            const int rb = row * 256;
            const int sw = (row & 7) << 4;
#pragma unroll
            for (int kt = 0; kt < KT; ++kt) {
                const f16x8 a = *reinterpret_cast<const f16x8*>(
                    tile + ((rb + kt * 64 + g * 16) ^ sw));
                acc[mt][0] = MFMA(a, bF[0][kt], acc[mt][0]);
                acc[mt][1] = MFMA(a, bF[1][kt], acc[mt][1]);
            }
        }

        // softmax over n for this wave's col (no max-shift: logits ~N(0,1.4))
        const float pxa = (float)pxa_lds[i][col];
        float den = 0.f, num = 0.f;
#pragma unroll
        for (int mt = 0; mt < MT; ++mt)
#pragma unroll
            for (int r = 0; r < 4; ++r) {
                if (mt == 3 && r >= 2) continue;     // n >= 52: never valid
                float t = pxa + acc[mt][1][r];
                t = fmaxf(t, 0.2f * t);              // leaky_relu(0.2)
                float p = __expf(t);
                if (mt == 3) p *= m0v;               // n=48,49 valid iff g==0
                den += p;
                num = fmaf(p, acc[mt][0][r], num);
            }
        den += __shfl_xor(den, 16); den += __shfl_xor(den, 32);
        num += __shfl_xor(num, 16); num += __shfl_xor(num, 32);
        if (g == 0)
            out[(b0 + i) * DD + col] = __fdividef(num, den);
    };

    // ---- prologue: tiles 0,1 -> LDS; tiles 2,3 -> regs ----
    load_tile(raA, 0);
    load_tile(raB, 1);
    write_tile(raA, tiles[0]);     // compiler-counted vmcnt on raA
    write_tile(raB, tiles[1]);
    load_tile(raA, 2);
    load_tile(raB, 3);
    asm volatile("s_waitcnt lgkmcnt(0)" ::: "memory");
    __builtin_amdgcn_sched_barrier(0);
    __builtin_amdgcn_s_barrier();  // tiles[0],[1] + pxa_lds visible

#pragma unroll 1
    for (int t0 = 0; t0 < NIT; t0 += 2) {
        // (a) regs -> LDS for tiles t0+2, t0+3
        write_tile(raA, tiles[(t0 + 2) & (NBUF - 1)]);
        write_tile(raB, tiles[(t0 + 3) & (NBUF - 1)]);
        // (b) issue loads for tiles t0+4, t0+5
        load_tile(raA, t0 + 4);
        load_tile(raB, t0 + 5);
        __builtin_amdgcn_sched_barrier(0);   // pin load-issue ABOVE compute

        // (c) compute + softmax two tiles, no syncs between
        compute_tile(t0);
        compute_tile(t0 + 1);

        // (d) one drain + one barrier per TWO tiles
        asm volatile("s_waitcnt lgkmcnt(0)" ::: "memory");
        __builtin_amdgcn_sched_barrier(0);
        __builtin_amdgcn_s_barrier();
    }
}

extern "C" void kernel_launch(void* const* d_in, const int* in_sizes, int n_in,
                              void* d_out, int out_size, void* d_ws, size_t ws_size,
                              hipStream_t stream) {
    const float* x   = (const float*)d_in[0];  // [B, D]
    const float* nbr = (const float*)d_in[1];  // [B, N, D]
    const float* W   = (const float*)d_in[2];  // [D, D]
    const float* A_w = (const float*)d_in[3];  // [2D, D]
    const float* A_b = (const float*)d_in[4];  // [D]
    float* out = (float*)d_out;                // [B, D]
    const int B = in_sizes[0] / DD;

    compute_WA<<<dim3(DD, 2), DD, 0, stream>>>(W, A_w);
    cvt_weights<<<3 * DD, DD, 0, stream>>>(W);
    const int grid = (B + NIT - 1) / NIT;      // 512 blocks = 2/CU, one round
    attn_mfma<<<grid, 512, 0, stream>>>(x, nbr, A_b, out, B);
}